// Round 7
// baseline (2054.014 us; speedup 1.0000x reference)
//
#include <hip/hip_runtime.h>
#include <math.h>

#define PI_D 3.14159265358979323846

#define REP64(M) M(0) M(1) M(2) M(3) M(4) M(5) M(6) M(7) M(8) M(9) M(10) M(11) \
    M(12) M(13) M(14) M(15) M(16) M(17) M(18) M(19) M(20) M(21) M(22) M(23) \
    M(24) M(25) M(26) M(27) M(28) M(29) M(30) M(31) M(32) M(33) M(34) M(35) \
    M(36) M(37) M(38) M(39) M(40) M(41) M(42) M(43) M(44) M(45) M(46) M(47) \
    M(48) M(49) M(50) M(51) M(52) M(53) M(54) M(55) M(56) M(57) M(58) M(59) \
    M(60) M(61) M(62) M(63)

// weight-row delivery from LDS: one float4 live at a time, broadcast ds_read_b128
#define FC4(V, s, H, n0, n1, n2, n3) \
    H##n0 = fmaf(V.x, s, H##n0); H##n1 = fmaf(V.y, s, H##n1); \
    H##n2 = fmaf(V.z, s, H##n2); H##n3 = fmaf(V.w, s, H##n3);

#define FMACOL_ALL(wb, s, H) { const float4* _w = (wb); float4 V; \
    V=_w[0];  FC4(V,s,H,0,1,2,3)     V=_w[1];  FC4(V,s,H,4,5,6,7) \
    V=_w[2];  FC4(V,s,H,8,9,10,11)   V=_w[3];  FC4(V,s,H,12,13,14,15) \
    V=_w[4];  FC4(V,s,H,16,17,18,19) V=_w[5];  FC4(V,s,H,20,21,22,23) \
    V=_w[6];  FC4(V,s,H,24,25,26,27) V=_w[7];  FC4(V,s,H,28,29,30,31) \
    V=_w[8];  FC4(V,s,H,32,33,34,35) V=_w[9];  FC4(V,s,H,36,37,38,39) \
    V=_w[10]; FC4(V,s,H,40,41,42,43) V=_w[11]; FC4(V,s,H,44,45,46,47) \
    V=_w[12]; FC4(V,s,H,48,49,50,51) V=_w[13]; FC4(V,s,H,52,53,54,55) \
    V=_w[14]; FC4(V,s,H,56,57,58,59) V=_w[15]; FC4(V,s,H,60,61,62,63) }

#define FR4(V, P, X, n0, n1, n2, n3) \
    P = fmaf(V.x, X##n0, P); P = fmaf(V.y, X##n1, P); \
    P = fmaf(V.z, X##n2, P); P = fmaf(V.w, X##n3, P);

#define FMAROW_ALL(wb, P, X) { const float4* _w = (wb); float4 V; \
    V=_w[0];  FR4(V,P##0,X,0,1,2,3)     V=_w[1];  FR4(V,P##1,X,4,5,6,7) \
    V=_w[2];  FR4(V,P##2,X,8,9,10,11)   V=_w[3];  FR4(V,P##3,X,12,13,14,15) \
    V=_w[4];  FR4(V,P##0,X,16,17,18,19) V=_w[5];  FR4(V,P##1,X,20,21,22,23) \
    V=_w[6];  FR4(V,P##2,X,24,25,26,27) V=_w[7];  FR4(V,P##3,X,28,29,30,31) \
    V=_w[8];  FR4(V,P##0,X,32,33,34,35) V=_w[9];  FR4(V,P##1,X,36,37,38,39) \
    V=_w[10]; FR4(V,P##2,X,40,41,42,43) V=_w[11]; FR4(V,P##3,X,44,45,46,47) \
    V=_w[12]; FR4(V,P##0,X,48,49,50,51) V=_w[13]; FR4(V,P##1,X,52,53,54,55) \
    V=_w[14]; FR4(V,P##2,X,56,57,58,59) V=_w[15]; FR4(V,P##3,X,60,61,62,63) }

// ---------------- tables ----------------
// tz2[z][k][2]: {2*cos(2pi z k/40)/163840, -2*sin(2pi z k/40)/163840}, k=0 row = {1/163840, 0}
__global__ void k_tables(float* tzf, float* tzi, float* tz2, float* txf, float* txi) {
    int t = blockIdx.x * blockDim.x + threadIdx.x;
    if (t < 320) {
        int z = t >> 3, k = t & 7;
        double ang = -2.0 * PI_D * (double)(z * k) / 40.0;
        tzf[t * 2] = (float)cos(ang); tzf[t * 2 + 1] = (float)sin(ang);
        tzi[t * 2] = (float)cos(-ang); tzi[t * 2 + 1] = (float)sin(-ang);
        double s = 1.0 / 163840.0;
        double f = (k == 0) ? s : 2.0 * s;
        tz2[t * 2] = (float)(f * cos(-ang));
        tz2[t * 2 + 1] = (k == 0) ? 0.0f : (float)(-f * sin(-ang));
    }
    if (t < 1472) {
        int xx = t / 23, m = t % 23;
        double ang = -2.0 * PI_D * (double)(xx * (m - 11)) / 64.0;
        txf[t * 2] = (float)cos(ang); txf[t * 2 + 1] = (float)sin(ang);
        txi[t * 2] = (float)cos(-ang); txi[t * 2 + 1] = (float)sin(-ang);
    }
}

// transposes: w2t[l][j][o]=w2[l][o][j]; wwt[l][i][o]=ww[l][o][i]; w1t[l][i][j]=w1[l][j][i]
__global__ void k_wtrans(const float* __restrict__ w2, const float* __restrict__ ww,
                         const float* __restrict__ w1,
                         float* __restrict__ w2t, float* __restrict__ wwt,
                         float* __restrict__ w1t) {
    int gid = blockIdx.x * blockDim.x + threadIdx.x;
    if (gid < 16384) {
        int l = gid >> 12, r = gid & 4095, o = r >> 6, i = r & 63;
        w2t[l * 4096 + i * 64 + o] = w2[l * 4096 + o * 64 + i];
        wwt[l * 4096 + i * 64 + o] = ww[l * 4096 + o * 64 + i];
        w1t[l * 4096 + i * 64 + o] = w1[l * 4096 + o * 64 + i];
    }
}

// ---------------- lift ----------------
__global__ void k_lift(const float* __restrict__ xin, const float* __restrict__ pw,
                       const float* __restrict__ pb, float* __restrict__ xo) {
    int gid = blockIdx.x * 256 + threadIdx.x;   // 327680 total
    int b = gid / 163840, p = gid % 163840;
    int y = p / 2560, xx = (p / 40) % 64, z = p % 40;
    float v[13];
#pragma unroll
    for (int i = 0; i < 10; i++) v[i] = xin[(size_t)gid * 10 + i];
    v[10] = (float)((double)y / 63.0);
    v[11] = (float)((double)xx / 63.0);
    v[12] = (float)((double)z / 39.0);
    size_t ob = (size_t)b * 10485760 + p;
    for (int c = 0; c < 64; c++) {
        float a = pb[c];
#pragma unroll
        for (int i = 0; i < 13; i++) a += pw[c * 13 + i] * v[i];
        xo[ob + (size_t)c * 163840] = a;
    }
}

// ---------------- forward z-DFT (r2c, 8 modes) fused with x-DFT (64 -> 23 modes) ----
__global__ void k_fwd_zx(const float* __restrict__ x, const float* __restrict__ tzf,
                         const float* __restrict__ txf, float* __restrict__ Fx) {
    int bid = blockIdx.x;
    int b = bid >> 12, c = (bid >> 6) & 63, y = bid & 63;
    int t = threadIdx.x;
    __shared__ float xr_[2560];
    __shared__ float f1[1024];
    __shared__ float tzs[640];
    const float* xrow = x + ((size_t)((b * 64 + c) * 4096 + y * 64)) * 40;
    for (int idx = t; idx < 2560; idx += 256) xr_[idx] = xrow[idx];
    for (int idx = t; idx < 640; idx += 256) tzs[idx] = tzf[idx];
    __syncthreads();
    for (int q = t; q < 512; q += 256) {
        int xx = q >> 3, k = q & 7;
        float sr = 0.f, si = 0.f;
        for (int z = 0; z < 40; z++) {
            float v = xr_[xx * 40 + z];
            sr += v * tzs[(z * 8 + k) * 2];
            si += v * tzs[(z * 8 + k) * 2 + 1];
        }
        f1[(xx * 8 + k) * 2] = sr;
        f1[(xx * 8 + k) * 2 + 1] = si;
    }
    __syncthreads();
    if (t < 184) {
        int m = t >> 3, k = t & 7;
        float sr = 0.f, si = 0.f;
        for (int xx = 0; xx < 64; xx++) {
            float ar = f1[(xx * 8 + k) * 2], ai = f1[(xx * 8 + k) * 2 + 1];
            float tr = txf[(xx * 23 + m) * 2], ti = txf[(xx * 23 + m) * 2 + 1];
            sr += ar * tr - ai * ti;
            si += ar * ti + ai * tr;
        }
        size_t g = ((size_t)(((b * 64 + c) * 64 + y) * 23 + m) * 8 + k) * 2;
        Fx[g] = sr; Fx[g + 1] = si;
    }
}

// ---------------- forward y-DFT (64 -> 23 modes) ----------------
__global__ void k_fwd_y(const float* __restrict__ Fx, const float* __restrict__ txf,
                        float* __restrict__ Xs) {
    int bid = blockIdx.x;
    int b = bid / 1472, rem = bid % 1472, c = rem / 23, m = rem % 23;
    int t = threadIdx.x;
    __shared__ float s[1024];  // [y][k][2]
    for (int idx = t; idx < 512; idx += 192) {
        int y = idx >> 3, k = idx & 7;
        size_t g = ((size_t)(((b * 64 + c) * 64 + y) * 23 + m) * 8 + k) * 2;
        s[idx * 2] = Fx[g]; s[idx * 2 + 1] = Fx[g + 1];
    }
    __syncthreads();
    if (t < 184) {
        int n = t >> 3, k = t & 7;
        float sr = 0.f, si = 0.f;
        for (int y = 0; y < 64; y++) {
            float ar = s[(y * 8 + k) * 2], ai = s[(y * 8 + k) * 2 + 1];
            float tr = txf[(y * 23 + n) * 2], ti = txf[(y * 23 + n) * 2 + 1];
            sr += ar * tr - ai * ti;
            si += ar * ti + ai * tr;
        }
        size_t g = ((size_t)(((b * 64 + c) * 23 + n) * 23 + m) * 8 + k) * 2;
        Xs[g] = sr; Xs[g + 1] = si;
    }
}

// ---------------- mode mixing with on-the-fly radial-weight gather ----------------
__global__ void k_mix(const float* __restrict__ Xs, const float* __restrict__ WLC,
                      const float* __restrict__ WLR, float* __restrict__ Md) {
    int bid = blockIdx.x;
    int n = bid / 23, m = bid % 23;
    int a = n, c = m, yy, w;
    if (c >= 11) { yy = a; w = c - 11; } else { yy = 22 - a; w = 11 - c; }
    int isLC, idx;
    if (yy >= 12) {
        int p = yy - 12, q = w;
        if (q == 0) { isLC = 1; idx = p + 1; } else { isLC = 0; idx = p * 11 + (q - 1); }
    } else {
        if (w == 0) { isLC = 1; idx = 11 - yy; }
        else {
            int p = w - 1, q = 11 - yy;
            if (q == 0) { isLC = 1; idx = p + 1; } else { isLC = 0; idx = p * 11 + (q - 1); }
        }
    }
    const float* src = isLC ? WLC : WLR;
    int stride = isLC ? 96 : 968;
    int base8 = idx * 8;

    int t = threadIdx.x;
    int o = t >> 3, tt = t & 7;
    __shared__ __align__(16) float wl[8 * 64 * 8];
    __shared__ float xl[256];
    float aR0 = 0.f, aI0 = 0.f, aR1 = 0.f, aI1 = 0.f;
    for (int i0 = 0; i0 < 64; i0 += 8) {
        {
            int il = t >> 6, oo = t & 63;
            const float4* g = (const float4*)(src + (size_t)((i0 + il) * 64 + oo) * stride + base8);
            float4 A = g[0], B = g[1];
            float4* d = (float4*)&wl[(il * 64 + oo) * 8];
            d[0] = A; d[1] = B;
        }
        if (t < 256) {
            int bb = t >> 7, il = (t >> 4) & 7, kk = (t >> 1) & 7, ri = t & 1;
            xl[t] = Xs[((size_t)(((bb * 64 + i0 + il) * 23 + n) * 23 + m) * 8 + kk) * 2 + ri];
        }
        __syncthreads();
#pragma unroll
        for (int il = 0; il < 8; il++) {
            float wv = wl[(il * 64 + o) * 8 + tt];
            float xr0 = xl[(il * 8 + tt) * 2], xi0 = xl[(il * 8 + tt) * 2 + 1];
            float xr1 = xl[128 + (il * 8 + tt) * 2], xi1 = xl[128 + (il * 8 + tt) * 2 + 1];
            aR0 += wv * xr0; aI0 += wv * xi0;
            aR1 += wv * xr1; aI1 += wv * xi1;
        }
        __syncthreads();
    }
    size_t ob0 = ((size_t)((o * 23 + n) * 23 + m) * 8 + tt) * 2;
    size_t ob1 = ((size_t)(((64 + o) * 23 + n) * 23 + m) * 8 + tt) * 2;
    Md[ob0] = aR0; Md[ob0 + 1] = aI0;
    Md[ob1] = aR1; Md[ob1 + 1] = aI1;
}

// ---------------- inverse y (23 -> 64) ----------------
__global__ void k_inv_y(const float* __restrict__ Md, const float* __restrict__ txi,
                        float* __restrict__ T1) {
    int bid = blockIdx.x;
    int b = bid / 1472, rem = bid % 1472, o = rem / 23, m = rem % 23;
    int t = threadIdx.x;
    __shared__ float s[368];  // [n][k][2]
    if (t < 184) {
        int n = t >> 3, kk = t & 7;
        size_t g = ((size_t)(((b * 64 + o) * 23 + n) * 23 + m) * 8 + kk) * 2;
        s[t * 2] = Md[g]; s[t * 2 + 1] = Md[g + 1];
    }
    __syncthreads();
    int y = t >> 3, k = t & 7;
    float sr = 0.f, si = 0.f;
    for (int n = 0; n < 23; n++) {
        float ar = s[(n * 8 + k) * 2], ai = s[(n * 8 + k) * 2 + 1];
        float tr = txi[(y * 23 + n) * 2], ti = txi[(y * 23 + n) * 2 + 1];
        sr += ar * tr - ai * ti;
        si += ar * ti + ai * tr;
    }
    size_t g = ((size_t)(((b * 64 + o) * 64 + y) * 23 + m) * 8 + k) * 2;
    T1[g] = sr; T1[g + 1] = si;
}

// ---------------- inverse x (23 -> 64) ----------------
__global__ void k_inv_x(const float* __restrict__ T1, const float* __restrict__ txi,
                        float* __restrict__ T2) {
    int bid = blockIdx.x;
    int b = bid >> 12, o = (bid >> 6) & 63, y = bid & 63;
    int t = threadIdx.x;
    __shared__ float s[368];  // [m][k][2]
    if (t < 184) {
        size_t g = (size_t)(((b * 64 + o) * 64 + y)) * 368 + t * 2;
        s[t * 2] = T1[g]; s[t * 2 + 1] = T1[g + 1];
    }
    __syncthreads();
    int xx = t >> 3, k = t & 7;
    float sr = 0.f, si = 0.f;
    for (int m = 0; m < 23; m++) {
        float ar = s[(m * 8 + k) * 2], ai = s[(m * 8 + k) * 2 + 1];
        float tr = txi[(xx * 23 + m) * 2], ti = txi[(xx * 23 + m) * 2 + 1];
        sr += ar * tr - ai * ti;
        si += ar * ti + ai * tr;
    }
    size_t g = ((size_t)((b * 64 + o) * 4096 + y * 64 + xx) * 8 + k) * 2;
    T2[g] = sr; T2[g + 1] = si;
}

// ---------------- inline erf-based GELU (A&S 7.1.26, |err|<=1.5e-7) ----
__device__ __forceinline__ float gelu_fast(float x) {
    float u = x * 0.70710678118654752f;
    float a = fabsf(u);
    float t = 1.0f / (1.0f + 0.3275911f * a);
    float poly = t * (0.254829592f + t * (-0.284496736f + t * (1.421413741f +
                 t * (-1.453152027f + t * 1.061405429f))));
    float erfa = 1.0f - poly * __expf(-a * a);
    float er = copysignf(erfa, u);
    return 0.5f * x * (1.0f + er);
}

// ---------------- mlp1: c2r inverse-z + GEMM1 + gelu -> g[j][P] ----------------
// 64 named accumulators; w1t (16 KB) staged in LDS, rows read as broadcast
// ds_read_b128 (fixes SGPR/VMEM weight-delivery stall of R5).
__global__ __launch_bounds__(256) void k_mlp1(
    const float* __restrict__ t2buf, const float* __restrict__ w1t,
    const float* __restrict__ b1, const float* __restrict__ tz2,
    float* __restrict__ g) {
    __shared__ float4 wls[1024];  // w1t[i][j] as quads (16 KB = whole layer)
    int t = threadIdx.x;
    for (int idx = t; idx < 1024; idx += 256) wls[idx] = ((const float4*)w1t)[idx];
    int gid = blockIdx.x * 256 + t;  // 327680
    int b = gid / 163840, p = gid % 163840;
    int y = p / 2560, xx = (p / 40) % 64, z = p % 40;
    const float4* tzp = (const float4*)(tz2 + z * 16);
    float4 Tz0 = tzp[0], Tz1 = tzp[1], Tz2 = tzp[2], Tz3 = tzp[3];
    float tc0 = Tz0.x;
    float tc1 = Tz0.z, ts1 = Tz0.w;
    float tc2 = Tz1.x, ts2 = Tz1.y, tc3 = Tz1.z, ts3 = Tz1.w;
    float tc4 = Tz2.x, ts4 = Tz2.y, tc5 = Tz2.z, ts5 = Tz2.w;
    float tc6 = Tz3.x, ts6 = Tz3.y, tc7 = Tz3.z, ts7 = Tz3.w;
    size_t rowbase = ((size_t)(b * 64) * 4096 + y * 64 + xx) * 16;
#define DECL(n) float h##n = b1[n];
    REP64(DECL)
#undef DECL
    __syncthreads();
    for (int i = 0; i < 64; i++) {
        const float4* rp = (const float4*)(t2buf + rowbase + (size_t)i * 65536);
        float4 A = rp[0], B = rp[1], C = rp[2], D = rp[3];
        float xi = A.x * tc0;              // k=0: Im(DC) dropped (pocketfft c2r)
        xi = fmaf(A.z, tc1, xi); xi = fmaf(A.w, ts1, xi);
        xi = fmaf(B.x, tc2, xi); xi = fmaf(B.y, ts2, xi);
        xi = fmaf(B.z, tc3, xi); xi = fmaf(B.w, ts3, xi);
        xi = fmaf(C.x, tc4, xi); xi = fmaf(C.y, ts4, xi);
        xi = fmaf(C.z, tc5, xi); xi = fmaf(C.w, ts5, xi);
        xi = fmaf(D.x, tc6, xi); xi = fmaf(D.y, ts6, xi);
        xi = fmaf(D.z, tc7, xi); xi = fmaf(D.w, ts7, xi);
        FMACOL_ALL(&wls[i * 16], xi, h)
    }
#define STO(n) g[(size_t)(n) * 327680 + gid] = gelu_fast(h##n);
    REP64(STO)
#undef STO
}

// ---------------- mlp2: GEMM2 + skip + relu, in-place on x ----------------
// wwt+w2t (32 KB) staged in LDS; 64 named accumulators; all x reads precede
// stores -> in-place safe.
__global__ __launch_bounds__(256) void k_mlp2(
    const float* __restrict__ g, float* __restrict__ x,
    const float* __restrict__ w2t, const float* __restrict__ b2,
    const float* __restrict__ wwt, const float* __restrict__ wb, int dorelu) {
    __shared__ float4 wls[2048];  // [0,1024)=wwt, [1024,2048)=w2t
    int t = threadIdx.x;
    for (int idx = t; idx < 1024; idx += 256) {
        wls[idx] = ((const float4*)wwt)[idx];
        wls[idx + 1024] = ((const float4*)w2t)[idx];
    }
    int gid = blockIdx.x * 256 + t;  // 327680
    int b = gid / 163840, p = gid % 163840;
    size_t colbase = (size_t)b * 10485760 + p;
#define DECL(n) float h##n = b2[n] + wb[n];
    REP64(DECL)
#undef DECL
    __syncthreads();
    for (int i = 0; i < 64; i++) {
        float xi = x[colbase + (size_t)i * 163840];
        FMACOL_ALL(&wls[i * 16], xi, h)
    }
    for (int j = 0; j < 64; j++) {
        float gj = g[(size_t)j * 327680 + gid];
        FMACOL_ALL(&wls[1024 + j * 16], gj, h)
    }
    if (dorelu) {
#define STO(n) x[colbase + (size_t)(n) * 163840] = fmaxf(h##n, 0.0f);
        REP64(STO)
#undef STO
    } else {
#define STO(n) x[colbase + (size_t)(n) * 163840] = h##n;
        REP64(STO)
#undef STO
    }
}

// ---------------- final head ----------------
// 64 named x regs; qw1 staged through LDS in 4 chunks of 64 rows (4096 floats
// each — NOT 16384: that was the R6 OOB bug); 4 interleaved partial sums.
__global__ __launch_bounds__(256) void k_head(
    const float* __restrict__ xcur,
    const float* __restrict__ qw1, const float* __restrict__ qb1,
    const float* __restrict__ qw2, const float* __restrict__ qb2,
    float* __restrict__ outp) {
    __shared__ float4 wls[1024];  // one 64-row chunk of qw1 (64*64 floats)
    int t = threadIdx.x;
    int gid = blockIdx.x * 256 + t;  // 327680
    int b = gid / 163840, p = gid % 163840;
    size_t base = (size_t)b * 10485760 + p;
#define LD(n) float x##n = xcur[base + (size_t)(n) * 163840];
    REP64(LD)
#undef LD
    float acc = qb2[0];
    for (int c = 0; c < 4; c++) {
        __syncthreads();
        const float4* src = (const float4*)(qw1 + c * 4096);  // 64 rows * 64 cols
        for (int idx = t; idx < 1024; idx += 256) wls[idx] = src[idx];
        __syncthreads();
        for (int jl = 0; jl < 64; jl++) {
            int j = c * 64 + jl;
            float p0 = 0.f, p1 = 0.f, p2 = 0.f, p3 = 0.f;
            FMAROW_ALL(&wls[jl * 16], p, x)
            float h = qb1[j] + ((p0 + p1) + (p2 + p3));
            acc += qw2[j] * gelu_fast(h);
        }
    }
    outp[gid] = acc;
}

extern "C" void kernel_launch(void* const* d_in, const int* in_sizes, int n_in,
                              void* d_out, int out_size, void* d_ws, size_t ws_size,
                              hipStream_t stream) {
    const float* x_in = (const float*)d_in[0];
    const float* p_w  = (const float*)d_in[1];
    const float* p_b  = (const float*)d_in[2];
    const float* W_LC = (const float*)d_in[3];
    const float* W_LR = (const float*)d_in[4];
    const float* m_w1 = (const float*)d_in[5];
    const float* m_b1 = (const float*)d_in[6];
    const float* m_w2 = (const float*)d_in[7];
    const float* m_b2 = (const float*)d_in[8];
    const float* w_w  = (const float*)d_in[9];
    const float* w_b  = (const float*)d_in[10];
    const float* q_w1 = (const float*)d_in[11];
    const float* q_b1 = (const float*)d_in[12];
    const float* q_w2 = (const float*)d_in[13];
    const float* q_b2 = (const float*)d_in[14];

    char* ws = (char*)d_ws;
    // packed table region [0, 32768)
    float* tzf = (float*)(ws + 0);        // 2560 B
    float* tzi = (float*)(ws + 2560);     // 2560 B
    float* tz2 = (float*)(ws + 5120);     // 2560 B (16B-aligned)
    float* txf = (float*)(ws + 7680);     // 11776 B
    float* txi = (float*)(ws + 19456);    // 11776 B -> ends 31232
    float* w2t = (float*)(ws + 32768);
    float* wwt = (float*)(ws + 98304);
    float* w1t = (float*)(ws + 163840);
    size_t off = 229376;
    float* xA = (float*)(ws + off); off += 83886080ull;
    float* gbuf = (float*)(ws + off); off += 83886080ull;   // g[j][P]
    float* Fx = (float*)(ws + off); off += 12058624ull;
    float* Xs = (float*)(ws + off); off += 4333568ull;
    float* Md = (float*)(ws + off); off += 4333568ull;
    float* T1 = (float*)(ws + off); off += 12058624ull;
    float* T2 = (float*)(ws + off); off += 33554432ull;

    k_tables<<<6, 256, 0, stream>>>(tzf, tzi, tz2, txf, txi);
    k_wtrans<<<64, 256, 0, stream>>>(m_w2, w_w, m_w1, w2t, wwt, w1t);
    k_lift<<<1280, 256, 0, stream>>>(x_in, p_w, p_b, xA);

    for (int l = 0; l < 4; l++) {
        k_fwd_zx<<<8192, 256, 0, stream>>>(xA, tzf, txf, Fx);
        k_fwd_y<<<2944, 192, 0, stream>>>(Fx, txf, Xs);
        k_mix<<<529, 512, 0, stream>>>(Xs, W_LC + (size_t)l * 393216,
                                       W_LR + (size_t)l * 3964928, Md);
        k_inv_y<<<2944, 512, 0, stream>>>(Md, txi, T1);
        k_inv_x<<<8192, 512, 0, stream>>>(T1, txi, T2);
        k_mlp1<<<1280, 256, 0, stream>>>(T2, w1t + (size_t)l * 4096, m_b1 + l * 64,
                                         tz2, gbuf);
        k_mlp2<<<1280, 256, 0, stream>>>(gbuf, xA, w2t + (size_t)l * 4096, m_b2 + l * 64,
                                         wwt + (size_t)l * 4096, w_b + l * 64,
                                         (l < 3) ? 1 : 0);
    }
    k_head<<<1280, 256, 0, stream>>>(xA, q_w1, q_b1, q_w2, q_b2, (float*)d_out);
}

// Round 8
// 1562.940 us; speedup vs baseline: 1.3142x; 1.3142x over previous
//
#include <hip/hip_runtime.h>
#include <math.h>

#define PI_D 3.14159265358979323846

#define REP64(M) M(0) M(1) M(2) M(3) M(4) M(5) M(6) M(7) M(8) M(9) M(10) M(11) \
    M(12) M(13) M(14) M(15) M(16) M(17) M(18) M(19) M(20) M(21) M(22) M(23) \
    M(24) M(25) M(26) M(27) M(28) M(29) M(30) M(31) M(32) M(33) M(34) M(35) \
    M(36) M(37) M(38) M(39) M(40) M(41) M(42) M(43) M(44) M(45) M(46) M(47) \
    M(48) M(49) M(50) M(51) M(52) M(53) M(54) M(55) M(56) M(57) M(58) M(59) \
    M(60) M(61) M(62) M(63)

// ---------------- tables ----------------
// tz2[z][k][2]: {2*cos(2pi z k/40)/163840, -2*sin(2pi z k/40)/163840}, k=0 row = {1/163840, 0}
__global__ void k_tables(float* tzf, float* tzi, float* tz2, float* txf, float* txi) {
    int t = blockIdx.x * blockDim.x + threadIdx.x;
    if (t < 320) {
        int z = t >> 3, k = t & 7;
        double ang = -2.0 * PI_D * (double)(z * k) / 40.0;
        tzf[t * 2] = (float)cos(ang); tzf[t * 2 + 1] = (float)sin(ang);
        tzi[t * 2] = (float)cos(-ang); tzi[t * 2 + 1] = (float)sin(-ang);
        double s = 1.0 / 163840.0;
        double f = (k == 0) ? s : 2.0 * s;
        tz2[t * 2] = (float)(f * cos(-ang));
        tz2[t * 2 + 1] = (k == 0) ? 0.0f : (float)(-f * sin(-ang));
    }
    if (t < 1472) {
        int xx = t / 23, m = t % 23;
        double ang = -2.0 * PI_D * (double)(xx * (m - 11)) / 64.0;
        txf[t * 2] = (float)cos(ang); txf[t * 2 + 1] = (float)sin(ang);
        txi[t * 2] = (float)cos(-ang); txi[t * 2 + 1] = (float)sin(-ang);
    }
}

// transposes: w2t[l][j][o]=w2[l][o][j]; wwt[l][i][o]=ww[l][o][i]; w1t[l][i][j]=w1[l][j][i]
__global__ void k_wtrans(const float* __restrict__ w2, const float* __restrict__ ww,
                         const float* __restrict__ w1,
                         float* __restrict__ w2t, float* __restrict__ wwt,
                         float* __restrict__ w1t) {
    int gid = blockIdx.x * blockDim.x + threadIdx.x;
    if (gid < 16384) {
        int l = gid >> 12, r = gid & 4095, o = r >> 6, i = r & 63;
        w2t[l * 4096 + i * 64 + o] = w2[l * 4096 + o * 64 + i];
        wwt[l * 4096 + i * 64 + o] = ww[l * 4096 + o * 64 + i];
        w1t[l * 4096 + i * 64 + o] = w1[l * 4096 + o * 64 + i];
    }
}

// ---------------- lift ----------------
__global__ void k_lift(const float* __restrict__ xin, const float* __restrict__ pw,
                       const float* __restrict__ pb, float* __restrict__ xo) {
    int gid = blockIdx.x * 256 + threadIdx.x;   // 327680 total
    int b = gid / 163840, p = gid % 163840;
    int y = p / 2560, xx = (p / 40) % 64, z = p % 40;
    float v[13];
#pragma unroll
    for (int i = 0; i < 10; i++) v[i] = xin[(size_t)gid * 10 + i];
    v[10] = (float)((double)y / 63.0);
    v[11] = (float)((double)xx / 63.0);
    v[12] = (float)((double)z / 39.0);
    size_t ob = (size_t)b * 10485760 + p;
    for (int c = 0; c < 64; c++) {
        float a = pb[c];
#pragma unroll
        for (int i = 0; i < 13; i++) a += pw[c * 13 + i] * v[i];
        xo[ob + (size_t)c * 163840] = a;
    }
}

// ---------------- forward z-DFT (r2c, 8 modes) fused with x-DFT (64 -> 23 modes) ----
__global__ void k_fwd_zx(const float* __restrict__ x, const float* __restrict__ tzf,
                         const float* __restrict__ txf, float* __restrict__ Fx) {
    int bid = blockIdx.x;
    int b = bid >> 12, c = (bid >> 6) & 63, y = bid & 63;
    int t = threadIdx.x;
    __shared__ float xr_[2560];
    __shared__ float f1[1024];
    __shared__ float tzs[640];
    const float* xrow = x + ((size_t)((b * 64 + c) * 4096 + y * 64)) * 40;
    for (int idx = t; idx < 2560; idx += 256) xr_[idx] = xrow[idx];
    for (int idx = t; idx < 640; idx += 256) tzs[idx] = tzf[idx];
    __syncthreads();
    for (int q = t; q < 512; q += 256) {
        int xx = q >> 3, k = q & 7;
        float sr = 0.f, si = 0.f;
        for (int z = 0; z < 40; z++) {
            float v = xr_[xx * 40 + z];
            sr += v * tzs[(z * 8 + k) * 2];
            si += v * tzs[(z * 8 + k) * 2 + 1];
        }
        f1[(xx * 8 + k) * 2] = sr;
        f1[(xx * 8 + k) * 2 + 1] = si;
    }
    __syncthreads();
    if (t < 184) {
        int m = t >> 3, k = t & 7;
        float sr = 0.f, si = 0.f;
        for (int xx = 0; xx < 64; xx++) {
            float ar = f1[(xx * 8 + k) * 2], ai = f1[(xx * 8 + k) * 2 + 1];
            float tr = txf[(xx * 23 + m) * 2], ti = txf[(xx * 23 + m) * 2 + 1];
            sr += ar * tr - ai * ti;
            si += ar * ti + ai * tr;
        }
        size_t g = ((size_t)(((b * 64 + c) * 64 + y) * 23 + m) * 8 + k) * 2;
        Fx[g] = sr; Fx[g + 1] = si;
    }
}

// ---------------- forward y-DFT (64 -> 23 modes) ----------------
__global__ void k_fwd_y(const float* __restrict__ Fx, const float* __restrict__ txf,
                        float* __restrict__ Xs) {
    int bid = blockIdx.x;
    int b = bid / 1472, rem = bid % 1472, c = rem / 23, m = rem % 23;
    int t = threadIdx.x;
    __shared__ float s[1024];  // [y][k][2]
    for (int idx = t; idx < 512; idx += 192) {
        int y = idx >> 3, k = idx & 7;
        size_t g = ((size_t)(((b * 64 + c) * 64 + y) * 23 + m) * 8 + k) * 2;
        s[idx * 2] = Fx[g]; s[idx * 2 + 1] = Fx[g + 1];
    }
    __syncthreads();
    if (t < 184) {
        int n = t >> 3, k = t & 7;
        float sr = 0.f, si = 0.f;
        for (int y = 0; y < 64; y++) {
            float ar = s[(y * 8 + k) * 2], ai = s[(y * 8 + k) * 2 + 1];
            float tr = txf[(y * 23 + n) * 2], ti = txf[(y * 23 + n) * 2 + 1];
            sr += ar * tr - ai * ti;
            si += ar * ti + ai * tr;
        }
        size_t g = ((size_t)(((b * 64 + c) * 23 + n) * 23 + m) * 8 + k) * 2;
        Xs[g] = sr; Xs[g + 1] = si;
    }
}

// ---------------- mode mixing with on-the-fly radial-weight gather ----------------
__global__ void k_mix(const float* __restrict__ Xs, const float* __restrict__ WLC,
                      const float* __restrict__ WLR, float* __restrict__ Md) {
    int bid = blockIdx.x;
    int n = bid / 23, m = bid % 23;
    int a = n, c = m, yy, w;
    if (c >= 11) { yy = a; w = c - 11; } else { yy = 22 - a; w = 11 - c; }
    int isLC, idx;
    if (yy >= 12) {
        int p = yy - 12, q = w;
        if (q == 0) { isLC = 1; idx = p + 1; } else { isLC = 0; idx = p * 11 + (q - 1); }
    } else {
        if (w == 0) { isLC = 1; idx = 11 - yy; }
        else {
            int p = w - 1, q = 11 - yy;
            if (q == 0) { isLC = 1; idx = p + 1; } else { isLC = 0; idx = p * 11 + (q - 1); }
        }
    }
    const float* src = isLC ? WLC : WLR;
    int stride = isLC ? 96 : 968;
    int base8 = idx * 8;

    int t = threadIdx.x;
    int o = t >> 3, tt = t & 7;
    __shared__ __align__(16) float wl[8 * 64 * 8];
    __shared__ float xl[256];
    float aR0 = 0.f, aI0 = 0.f, aR1 = 0.f, aI1 = 0.f;
    for (int i0 = 0; i0 < 64; i0 += 8) {
        {
            int il = t >> 6, oo = t & 63;
            const float4* g = (const float4*)(src + (size_t)((i0 + il) * 64 + oo) * stride + base8);
            float4 A = g[0], B = g[1];
            float4* d = (float4*)&wl[(il * 64 + oo) * 8];
            d[0] = A; d[1] = B;
        }
        if (t < 256) {
            int bb = t >> 7, il = (t >> 4) & 7, kk = (t >> 1) & 7, ri = t & 1;
            xl[t] = Xs[((size_t)(((bb * 64 + i0 + il) * 23 + n) * 23 + m) * 8 + kk) * 2 + ri];
        }
        __syncthreads();
#pragma unroll
        for (int il = 0; il < 8; il++) {
            float wv = wl[(il * 64 + o) * 8 + tt];
            float xr0 = xl[(il * 8 + tt) * 2], xi0 = xl[(il * 8 + tt) * 2 + 1];
            float xr1 = xl[128 + (il * 8 + tt) * 2], xi1 = xl[128 + (il * 8 + tt) * 2 + 1];
            aR0 += wv * xr0; aI0 += wv * xi0;
            aR1 += wv * xr1; aI1 += wv * xi1;
        }
        __syncthreads();
    }
    size_t ob0 = ((size_t)((o * 23 + n) * 23 + m) * 8 + tt) * 2;
    size_t ob1 = ((size_t)(((64 + o) * 23 + n) * 23 + m) * 8 + tt) * 2;
    Md[ob0] = aR0; Md[ob0 + 1] = aI0;
    Md[ob1] = aR1; Md[ob1 + 1] = aI1;
}

// ---------------- inverse y (23 -> 64) ----------------
__global__ void k_inv_y(const float* __restrict__ Md, const float* __restrict__ txi,
                        float* __restrict__ T1) {
    int bid = blockIdx.x;
    int b = bid / 1472, rem = bid % 1472, o = rem / 23, m = rem % 23;
    int t = threadIdx.x;
    __shared__ float s[368];  // [n][k][2]
    if (t < 184) {
        int n = t >> 3, kk = t & 7;
        size_t g = ((size_t)(((b * 64 + o) * 23 + n) * 23 + m) * 8 + kk) * 2;
        s[t * 2] = Md[g]; s[t * 2 + 1] = Md[g + 1];
    }
    __syncthreads();
    int y = t >> 3, k = t & 7;
    float sr = 0.f, si = 0.f;
    for (int n = 0; n < 23; n++) {
        float ar = s[(n * 8 + k) * 2], ai = s[(n * 8 + k) * 2 + 1];
        float tr = txi[(y * 23 + n) * 2], ti = txi[(y * 23 + n) * 2 + 1];
        sr += ar * tr - ai * ti;
        si += ar * ti + ai * tr;
    }
    size_t g = ((size_t)(((b * 64 + o) * 64 + y) * 23 + m) * 8 + k) * 2;
    T1[g] = sr; T1[g + 1] = si;
}

// ---------------- inverse x (23 -> 64) ----------------
__global__ void k_inv_x(const float* __restrict__ T1, const float* __restrict__ txi,
                        float* __restrict__ T2) {
    int bid = blockIdx.x;
    int b = bid >> 12, o = (bid >> 6) & 63, y = bid & 63;
    int t = threadIdx.x;
    __shared__ float s[368];  // [m][k][2]
    if (t < 184) {
        size_t g = (size_t)(((b * 64 + o) * 64 + y)) * 368 + t * 2;
        s[t * 2] = T1[g]; s[t * 2 + 1] = T1[g + 1];
    }
    __syncthreads();
    int xx = t >> 3, k = t & 7;
    float sr = 0.f, si = 0.f;
    for (int m = 0; m < 23; m++) {
        float ar = s[(m * 8 + k) * 2], ai = s[(m * 8 + k) * 2 + 1];
        float tr = txi[(xx * 23 + m) * 2], ti = txi[(xx * 23 + m) * 2 + 1];
        sr += ar * tr - ai * ti;
        si += ar * ti + ai * tr;
    }
    size_t g = ((size_t)((b * 64 + o) * 4096 + y * 64 + xx) * 8 + k) * 2;
    T2[g] = sr; T2[g + 1] = si;
}

// ---------------- inline erf-based GELU (A&S 7.1.26, |err|<=1.5e-7) ----
__device__ __forceinline__ float gelu_fast(float x) {
    float u = x * 0.70710678118654752f;
    float a = fabsf(u);
    float t = 1.0f / (1.0f + 0.3275911f * a);
    float poly = t * (0.254829592f + t * (-0.284496736f + t * (1.421413741f +
                 t * (-1.453152027f + t * 1.061405429f))));
    float erfa = 1.0f - poly * __expf(-a * a);
    float er = copysignf(erfa, u);
    return 0.5f * x * (1.0f + er);
}

// ---------------- mlp1 v2: k-space GEMM (w1 folded before c2r) + c2r + gelu ----
// GEMM1 commutes with inverse-z DFT: H[j] = sum_i w1[j][i]*T2row[i] on 16-float
// k-rows (8192 sites), then h = b1[j] + c2r_z(H) per z. 2.5x fewer GEMM FLOPs,
// T2 read exactly once. 4 sites/block, 4j x 4kr register tiles.
__global__ __launch_bounds__(256) void k_mlp1(
    const float* __restrict__ t2buf, const float* __restrict__ w1t,
    const float* __restrict__ b1, const float* __restrict__ tz2g,
    float* __restrict__ g) {
    __shared__ __align__(16) float T2s[4096];   // [4 sites][64 i][16]
    __shared__ __align__(16) float w1ls[4096];  // [64 i][64 j]
    __shared__ __align__(16) float Hs[4096];    // [4 sites][64 j][16]
    __shared__ float tzls[640];
    int t = threadIdx.x;
    int site0 = blockIdx.x * 4;
    // stage T2 rows for 4 sites (each 64 B segments, coalesced in q)
    for (int idx = t; idx < 1024; idx += 256) {
        int sl = idx >> 8, r = idx & 255, i = r >> 2, q = r & 3;
        int site = site0 + sl;
        int b = site >> 12, yx = site & 4095;
        const float4* src = (const float4*)(t2buf + ((size_t)(b * 64 + i) * 4096 + yx) * 16 + q * 4);
        *(float4*)&T2s[sl * 1024 + i * 16 + q * 4] = *src;
    }
    for (int idx = t; idx < 1024; idx += 256)
        *(float4*)&w1ls[idx * 4] = ((const float4*)w1t)[idx];
    for (int idx = t; idx < 640; idx += 256) tzls[idx] = tz2g[idx];
    __syncthreads();
    // phase A: per-site GEMM 64j x 16kr, tiles 4j x 4kr
    {
        int sl = t >> 6, u = t & 63;
        int j0 = (u >> 2) * 4, kr0 = (u & 3) * 4;
        float c0 = 0.f, c1 = 0.f, c2 = 0.f, c3 = 0.f, c4 = 0.f, c5 = 0.f, c6 = 0.f, c7 = 0.f;
        float c8 = 0.f, c9 = 0.f, c10 = 0.f, c11 = 0.f, c12 = 0.f, c13 = 0.f, c14 = 0.f, c15 = 0.f;
        int tb = sl * 1024 + kr0;
        for (int i = 0; i < 64; i++) {
            float4 W = *(const float4*)&w1ls[i * 64 + j0];
            float4 T = *(const float4*)&T2s[tb + i * 16];
            c0  = fmaf(W.x, T.x, c0);  c1  = fmaf(W.x, T.y, c1);
            c2  = fmaf(W.x, T.z, c2);  c3  = fmaf(W.x, T.w, c3);
            c4  = fmaf(W.y, T.x, c4);  c5  = fmaf(W.y, T.y, c5);
            c6  = fmaf(W.y, T.z, c6);  c7  = fmaf(W.y, T.w, c7);
            c8  = fmaf(W.z, T.x, c8);  c9  = fmaf(W.z, T.y, c9);
            c10 = fmaf(W.z, T.z, c10); c11 = fmaf(W.z, T.w, c11);
            c12 = fmaf(W.w, T.x, c12); c13 = fmaf(W.w, T.y, c13);
            c14 = fmaf(W.w, T.z, c14); c15 = fmaf(W.w, T.w, c15);
        }
        int hb = sl * 1024 + j0 * 16 + kr0;
        *(float4*)&Hs[hb]      = make_float4(c0, c1, c2, c3);
        *(float4*)&Hs[hb + 16] = make_float4(c4, c5, c6, c7);
        *(float4*)&Hs[hb + 32] = make_float4(c8, c9, c10, c11);
        *(float4*)&Hs[hb + 48] = make_float4(c12, c13, c14, c15);
    }
    __syncthreads();
    // phase B: thread = (site, j); c2r over z + gelu, float4 stores
    {
        int sl = t >> 6, j = t & 63;
        int site = site0 + sl;
        int b = site >> 12, yx = site & 4095;
        int hb = sl * 1024 + j * 16;
        float4 H0 = *(const float4*)&Hs[hb];
        float4 H1 = *(const float4*)&Hs[hb + 4];
        float4 H2 = *(const float4*)&Hs[hb + 8];
        float4 H3 = *(const float4*)&Hs[hb + 12];
        float b1j = b1[j];
        size_t obase = (size_t)j * 327680 + (size_t)b * 163840 + yx * 40;
        for (int zc = 0; zc < 10; zc++) {
            float4 outv;
#pragma unroll
            for (int zi = 0; zi < 4; zi++) {
                int z = zc * 4 + zi;
                const float4* tz = (const float4*)&tzls[z * 16];
                float4 T0 = tz[0], T1v = tz[1], T2v = tz[2], T3 = tz[3];
                float v = H0.x * T0.x;
                v = fmaf(H0.y, T0.y, v); v = fmaf(H0.z, T0.z, v); v = fmaf(H0.w, T0.w, v);
                v = fmaf(H1.x, T1v.x, v); v = fmaf(H1.y, T1v.y, v);
                v = fmaf(H1.z, T1v.z, v); v = fmaf(H1.w, T1v.w, v);
                v = fmaf(H2.x, T2v.x, v); v = fmaf(H2.y, T2v.y, v);
                v = fmaf(H2.z, T2v.z, v); v = fmaf(H2.w, T2v.w, v);
                v = fmaf(H3.x, T3.x, v); v = fmaf(H3.y, T3.y, v);
                v = fmaf(H3.z, T3.z, v); v = fmaf(H3.w, T3.w, v);
                float h = b1j + v;
                float gv = gelu_fast(h);
                if (zi == 0) outv.x = gv; else if (zi == 1) outv.y = gv;
                else if (zi == 2) outv.z = gv; else outv.w = gv;
            }
            *(float4*)&g[obase + zc * 4] = outv;
        }
    }
}

// ---------------- mlp2 v2: two-phase 8o x 4p register-tiled GEMM, in-place ----
// Block = 128 points x 64 o. Phase 1: skip (wwt, x); phase 2: GEMM2 (w2t, g).
// 32 FMA per 3 ds_read_b128. In-place safe: x staged before any store.
#define FMA8x4(W0, W1, X) \
    a0  = fmaf(W0.x, X.x, a0);  a1  = fmaf(W0.x, X.y, a1);  a2  = fmaf(W0.x, X.z, a2);  a3  = fmaf(W0.x, X.w, a3); \
    a4  = fmaf(W0.y, X.x, a4);  a5  = fmaf(W0.y, X.y, a5);  a6  = fmaf(W0.y, X.z, a6);  a7  = fmaf(W0.y, X.w, a7); \
    a8  = fmaf(W0.z, X.x, a8);  a9  = fmaf(W0.z, X.y, a9);  a10 = fmaf(W0.z, X.z, a10); a11 = fmaf(W0.z, X.w, a11); \
    a12 = fmaf(W0.w, X.x, a12); a13 = fmaf(W0.w, X.y, a13); a14 = fmaf(W0.w, X.z, a14); a15 = fmaf(W0.w, X.w, a15); \
    a16 = fmaf(W1.x, X.x, a16); a17 = fmaf(W1.x, X.y, a17); a18 = fmaf(W1.x, X.z, a18); a19 = fmaf(W1.x, X.w, a19); \
    a20 = fmaf(W1.y, X.x, a20); a21 = fmaf(W1.y, X.y, a21); a22 = fmaf(W1.y, X.z, a22); a23 = fmaf(W1.y, X.w, a23); \
    a24 = fmaf(W1.z, X.x, a24); a25 = fmaf(W1.z, X.y, a25); a26 = fmaf(W1.z, X.z, a26); a27 = fmaf(W1.z, X.w, a27); \
    a28 = fmaf(W1.w, X.x, a28); a29 = fmaf(W1.w, X.y, a29); a30 = fmaf(W1.w, X.z, a30); a31 = fmaf(W1.w, X.w, a31);

__global__ __launch_bounds__(256) void k_mlp2(
    const float* __restrict__ g, float* __restrict__ x,
    const float* __restrict__ w2t, const float* __restrict__ b2,
    const float* __restrict__ wwt, const float* __restrict__ wb, int dorelu) {
    __shared__ __align__(16) float vs[8192];   // [64 i][128 p]
    __shared__ __align__(16) float wls[4096];  // [64 i][64 o]
    int t = threadIdx.x;
    int P0 = blockIdx.x * 128;
    int b = P0 / 163840, pl = P0 % 163840;
    size_t xbase = (size_t)b * 10485760 + pl;
    // stage phase 1: x-tile + wwt
    for (int idx = t; idx < 2048; idx += 256) {
        int i = idx >> 5, pp = (idx & 31) * 4;
        *(float4*)&vs[i * 128 + pp] = *(const float4*)(x + xbase + (size_t)i * 163840 + pp);
    }
    for (int idx = t; idx < 1024; idx += 256)
        *(float4*)&wls[idx * 4] = ((const float4*)wwt)[idx];
    int o0 = (t >> 5) * 8, p0 = (t & 31) * 4;
    float a0  = b2[o0]     + wb[o0],     a1  = a0, a2  = a0, a3  = a0;
    float a4  = b2[o0 + 1] + wb[o0 + 1], a5  = a4, a6  = a4, a7  = a4;
    float a8  = b2[o0 + 2] + wb[o0 + 2], a9  = a8, a10 = a8, a11 = a8;
    float a12 = b2[o0 + 3] + wb[o0 + 3], a13 = a12, a14 = a12, a15 = a12;
    float a16 = b2[o0 + 4] + wb[o0 + 4], a17 = a16, a18 = a16, a19 = a16;
    float a20 = b2[o0 + 5] + wb[o0 + 5], a21 = a20, a22 = a20, a23 = a20;
    float a24 = b2[o0 + 6] + wb[o0 + 6], a25 = a24, a26 = a24, a27 = a24;
    float a28 = b2[o0 + 7] + wb[o0 + 7], a29 = a28, a30 = a28, a31 = a28;
    __syncthreads();
    for (int i = 0; i < 64; i++) {
        const float4* wp = (const float4*)&wls[i * 64 + o0];
        float4 W0 = wp[0], W1 = wp[1];
        float4 X = *(const float4*)&vs[i * 128 + p0];
        FMA8x4(W0, W1, X)
    }
    __syncthreads();
    // stage phase 2: g-tile + w2t
    for (int idx = t; idx < 2048; idx += 256) {
        int j = idx >> 5, pp = (idx & 31) * 4;
        *(float4*)&vs[j * 128 + pp] = *(const float4*)(g + (size_t)j * 327680 + P0 + pp);
    }
    for (int idx = t; idx < 1024; idx += 256)
        *(float4*)&wls[idx * 4] = ((const float4*)w2t)[idx];
    __syncthreads();
    for (int j = 0; j < 64; j++) {
        const float4* wp = (const float4*)&wls[j * 64 + o0];
        float4 W0 = wp[0], W1 = wp[1];
        float4 X = *(const float4*)&vs[j * 128 + p0];
        FMA8x4(W0, W1, X)
    }
    // store 8 float4 rows (coalesced across pg lanes)
#define STROW(oo, r0, r1, r2, r3) { \
        float4 R; \
        if (dorelu) R = make_float4(fmaxf(r0, 0.f), fmaxf(r1, 0.f), fmaxf(r2, 0.f), fmaxf(r3, 0.f)); \
        else R = make_float4(r0, r1, r2, r3); \
        *(float4*)(x + xbase + (size_t)(o0 + oo) * 163840 + p0) = R; }
    STROW(0, a0, a1, a2, a3)
    STROW(1, a4, a5, a6, a7)
    STROW(2, a8, a9, a10, a11)
    STROW(3, a12, a13, a14, a15)
    STROW(4, a16, a17, a18, a19)
    STROW(5, a20, a21, a22, a23)
    STROW(6, a24, a25, a26, a27)
    STROW(7, a28, a29, a30, a31)
#undef STROW
}

// ---------------- final head: 2 points/thread, shared broadcast weight rows ----
#define FR24(V, PA, PB, n0, n1, n2, n3) \
    PA = fmaf(V.x, xa##n0, PA); PB = fmaf(V.x, xb##n0, PB); \
    PA = fmaf(V.y, xa##n1, PA); PB = fmaf(V.y, xb##n1, PB); \
    PA = fmaf(V.z, xa##n2, PA); PB = fmaf(V.z, xb##n2, PB); \
    PA = fmaf(V.w, xa##n3, PA); PB = fmaf(V.w, xb##n3, PB);

#define FMAROW2_ALL(wb) { const float4* _w = (wb); float4 V; \
    V=_w[0];  FR24(V,pa0,pb0,0,1,2,3)     V=_w[1];  FR24(V,pa1,pb1,4,5,6,7) \
    V=_w[2];  FR24(V,pa2,pb2,8,9,10,11)   V=_w[3];  FR24(V,pa3,pb3,12,13,14,15) \
    V=_w[4];  FR24(V,pa0,pb0,16,17,18,19) V=_w[5];  FR24(V,pa1,pb1,20,21,22,23) \
    V=_w[6];  FR24(V,pa2,pb2,24,25,26,27) V=_w[7];  FR24(V,pa3,pb3,28,29,30,31) \
    V=_w[8];  FR24(V,pa0,pb0,32,33,34,35) V=_w[9];  FR24(V,pa1,pb1,36,37,38,39) \
    V=_w[10]; FR24(V,pa2,pb2,40,41,42,43) V=_w[11]; FR24(V,pa3,pb3,44,45,46,47) \
    V=_w[12]; FR24(V,pa0,pb0,48,49,50,51) V=_w[13]; FR24(V,pa1,pb1,52,53,54,55) \
    V=_w[14]; FR24(V,pa2,pb2,56,57,58,59) V=_w[15]; FR24(V,pa3,pb3,60,61,62,63) }

__global__ __launch_bounds__(256, 3) void k_head(
    const float* __restrict__ xcur,
    const float* __restrict__ qw1, const float* __restrict__ qb1,
    const float* __restrict__ qw2, const float* __restrict__ qb2,
    float* __restrict__ outp) {
    __shared__ float4 wls[1024];  // one 64-row chunk of qw1
    int t = threadIdx.x;
    int P0 = blockIdx.x * 512;
    int b = P0 / 163840, pl = P0 % 163840;
    size_t baseA = (size_t)b * 10485760 + pl + t;
    size_t baseB = baseA + 256;
#define LDA(n) float xa##n = xcur[baseA + (size_t)(n) * 163840];
    REP64(LDA)
#undef LDA
#define LDB(n) float xb##n = xcur[baseB + (size_t)(n) * 163840];
    REP64(LDB)
#undef LDB
    float accA = qb2[0], accB = qb2[0];
    for (int c = 0; c < 4; c++) {
        __syncthreads();
        const float4* src = (const float4*)(qw1 + c * 4096);  // 64 rows x 64 cols
        for (int idx = t; idx < 1024; idx += 256) wls[idx] = src[idx];
        __syncthreads();
        for (int jl = 0; jl < 64; jl++) {
            int j = c * 64 + jl;
            float pa0 = 0.f, pa1 = 0.f, pa2 = 0.f, pa3 = 0.f;
            float pb0 = 0.f, pb1 = 0.f, pb2 = 0.f, pb3 = 0.f;
            FMAROW2_ALL(&wls[jl * 16])
            float bj = qb1[j], wj = qw2[j];
            float hA = bj + ((pa0 + pa1) + (pa2 + pa3));
            float hB = bj + ((pb0 + pb1) + (pb2 + pb3));
            accA += wj * gelu_fast(hA);
            accB += wj * gelu_fast(hB);
        }
    }
    outp[P0 + t] = accA;
    outp[P0 + 256 + t] = accB;
}

extern "C" void kernel_launch(void* const* d_in, const int* in_sizes, int n_in,
                              void* d_out, int out_size, void* d_ws, size_t ws_size,
                              hipStream_t stream) {
    const float* x_in = (const float*)d_in[0];
    const float* p_w  = (const float*)d_in[1];
    const float* p_b  = (const float*)d_in[2];
    const float* W_LC = (const float*)d_in[3];
    const float* W_LR = (const float*)d_in[4];
    const float* m_w1 = (const float*)d_in[5];
    const float* m_b1 = (const float*)d_in[6];
    const float* m_w2 = (const float*)d_in[7];
    const float* m_b2 = (const float*)d_in[8];
    const float* w_w  = (const float*)d_in[9];
    const float* w_b  = (const float*)d_in[10];
    const float* q_w1 = (const float*)d_in[11];
    const float* q_b1 = (const float*)d_in[12];
    const float* q_w2 = (const float*)d_in[13];
    const float* q_b2 = (const float*)d_in[14];

    char* ws = (char*)d_ws;
    // packed table region [0, 32768)
    float* tzf = (float*)(ws + 0);        // 2560 B
    float* tzi = (float*)(ws + 2560);     // 2560 B
    float* tz2 = (float*)(ws + 5120);     // 2560 B (16B-aligned)
    float* txf = (float*)(ws + 7680);     // 11776 B
    float* txi = (float*)(ws + 19456);    // 11776 B -> ends 31232
    float* w2t = (float*)(ws + 32768);
    float* wwt = (float*)(ws + 98304);
    float* w1t = (float*)(ws + 163840);
    size_t off = 229376;
    float* xA = (float*)(ws + off); off += 83886080ull;
    float* gbuf = (float*)(ws + off); off += 83886080ull;   // g[j][P]
    float* Fx = (float*)(ws + off); off += 12058624ull;
    float* Xs = (float*)(ws + off); off += 4333568ull;
    float* Md = (float*)(ws + off); off += 4333568ull;
    float* T1 = (float*)(ws + off); off += 12058624ull;
    float* T2 = (float*)(ws + off); off += 33554432ull;

    k_tables<<<6, 256, 0, stream>>>(tzf, tzi, tz2, txf, txi);
    k_wtrans<<<64, 256, 0, stream>>>(m_w2, w_w, m_w1, w2t, wwt, w1t);
    k_lift<<<1280, 256, 0, stream>>>(x_in, p_w, p_b, xA);

    for (int l = 0; l < 4; l++) {
        k_fwd_zx<<<8192, 256, 0, stream>>>(xA, tzf, txf, Fx);
        k_fwd_y<<<2944, 192, 0, stream>>>(Fx, txf, Xs);
        k_mix<<<529, 512, 0, stream>>>(Xs, W_LC + (size_t)l * 393216,
                                       W_LR + (size_t)l * 3964928, Md);
        k_inv_y<<<2944, 512, 0, stream>>>(Md, txi, T1);
        k_inv_x<<<8192, 512, 0, stream>>>(T1, txi, T2);
        k_mlp1<<<2048, 256, 0, stream>>>(T2, w1t + (size_t)l * 4096, m_b1 + l * 64,
                                         tz2, gbuf);
        k_mlp2<<<2560, 256, 0, stream>>>(gbuf, xA, w2t + (size_t)l * 4096, m_b2 + l * 64,
                                         wwt + (size_t)l * 4096, w_b + l * 64,
                                         (l < 3) ? 1 : 0);
    }
    k_head<<<640, 256, 0, stream>>>(xA, q_w1, q_b1, q_w2, q_b2, (float*)d_out);
}

// Round 9
// 1300.297 us; speedup vs baseline: 1.5796x; 1.2020x over previous
//
#include <hip/hip_runtime.h>
#include <math.h>

#define PI_D 3.14159265358979323846

#define REP64(M) M(0) M(1) M(2) M(3) M(4) M(5) M(6) M(7) M(8) M(9) M(10) M(11) \
    M(12) M(13) M(14) M(15) M(16) M(17) M(18) M(19) M(20) M(21) M(22) M(23) \
    M(24) M(25) M(26) M(27) M(28) M(29) M(30) M(31) M(32) M(33) M(34) M(35) \
    M(36) M(37) M(38) M(39) M(40) M(41) M(42) M(43) M(44) M(45) M(46) M(47) \
    M(48) M(49) M(50) M(51) M(52) M(53) M(54) M(55) M(56) M(57) M(58) M(59) \
    M(60) M(61) M(62) M(63)

// ---------------- tables ----------------
// tz2[z][k][2]: c2r twiddles {2c/S, -2s/S}; tzk[k][z][2]: forward z twiddles {c,s}
__global__ void k_tables(float* tzf, float* tzi, float* tz2, float* tzk,
                         float* txf, float* txi) {
    int t = blockIdx.x * blockDim.x + threadIdx.x;
    if (t < 320) {
        int z = t >> 3, k = t & 7;
        double ang = -2.0 * PI_D * (double)(z * k) / 40.0;
        tzf[t * 2] = (float)cos(ang); tzf[t * 2 + 1] = (float)sin(ang);
        tzi[t * 2] = (float)cos(-ang); tzi[t * 2 + 1] = (float)sin(-ang);
        double s = 1.0 / 163840.0;
        double f = (k == 0) ? s : 2.0 * s;
        tz2[t * 2] = (float)(f * cos(-ang));
        tz2[t * 2 + 1] = (k == 0) ? 0.0f : (float)(-f * sin(-ang));
        tzk[(k * 40 + z) * 2] = (float)cos(ang);
        tzk[(k * 40 + z) * 2 + 1] = (float)sin(ang);
    }
    if (t < 1472) {
        int xx = t / 23, m = t % 23;
        double ang = -2.0 * PI_D * (double)(xx * (m - 11)) / 64.0;
        txf[t * 2] = (float)cos(ang); txf[t * 2 + 1] = (float)sin(ang);
        txi[t * 2] = (float)cos(-ang); txi[t * 2 + 1] = (float)sin(-ang);
    }
}

// transposes: w2t[l][j][o]=w2[l][o][j]; wwt[l][i][o]=ww[l][o][i]; w1t[l][i][j]=w1[l][j][i]
__global__ void k_wtrans(const float* __restrict__ w2, const float* __restrict__ ww,
                         const float* __restrict__ w1,
                         float* __restrict__ w2t, float* __restrict__ wwt,
                         float* __restrict__ w1t) {
    int gid = blockIdx.x * blockDim.x + threadIdx.x;
    if (gid < 16384) {
        int l = gid >> 12, r = gid & 4095, o = r >> 6, i = r & 63;
        w2t[l * 4096 + i * 64 + o] = w2[l * 4096 + o * 64 + i];
        wwt[l * 4096 + i * 64 + o] = ww[l * 4096 + o * 64 + i];
        w1t[l * 4096 + i * 64 + o] = w1[l * 4096 + o * 64 + i];
    }
}

// ---------------- lift ----------------
__global__ void k_lift(const float* __restrict__ xin, const float* __restrict__ pw,
                       const float* __restrict__ pb, float* __restrict__ xo) {
    int gid = blockIdx.x * 256 + threadIdx.x;   // 327680 total
    int b = gid / 163840, p = gid % 163840;
    int y = p / 2560, xx = (p / 40) % 64, z = p % 40;
    float v[13];
#pragma unroll
    for (int i = 0; i < 10; i++) v[i] = xin[(size_t)gid * 10 + i];
    v[10] = (float)((double)y / 63.0);
    v[11] = (float)((double)xx / 63.0);
    v[12] = (float)((double)z / 39.0);
    size_t ob = (size_t)b * 10485760 + p;
    for (int c = 0; c < 64; c++) {
        float a = pb[c];
#pragma unroll
        for (int i = 0; i < 13; i++) a += pw[c * 13 + i] * v[i];
        xo[ob + (size_t)c * 163840] = a;
    }
}

// ---------------- forward z-DFT + x-DFT, b128/b64 LDS reads ----------------
// grid (b,c,y)=8192, 256 threads. phase1: thread owns (xx, xx+32) sharing one
// twiddle stream: 6 LDS insts / 16 FMA per 4-z chunk. phase2: all-b64.
__global__ __launch_bounds__(256) void k_fwd_zx(const float* __restrict__ x,
        const float* __restrict__ tzk, const float* __restrict__ txf,
        float* __restrict__ Fx) {
    int bid = blockIdx.x;
    int b = bid >> 12, c = (bid >> 6) & 63, y = bid & 63;
    int t = threadIdx.x;
    __shared__ __align__(16) float xr_[2560];
    __shared__ __align__(16) float tzs[672];   // [k][42 f2] rows padded to 84 floats
    __shared__ __align__(16) float txs[2944];  // [xx][m][2]
    __shared__ __align__(16) float f1[1024];   // [xx][k][2]
    const float4* xrow4 = (const float4*)(x + ((size_t)((b * 64 + c) * 4096 + y * 64)) * 40);
    for (int idx = t; idx < 640; idx += 256) ((float4*)xr_)[idx] = xrow4[idx];
    for (int idx = t; idx < 160; idx += 256) {
        int k = idx / 20, q = idx % 20;
        ((float4*)tzs)[k * 21 + q] = ((const float4*)tzk)[idx];
    }
    for (int idx = t; idx < 736; idx += 256) ((float4*)txs)[idx] = ((const float4*)txf)[idx];
    __syncthreads();
    {
        int xx = t >> 3, k = t & 7;
        float sr0 = 0.f, si0 = 0.f, sr1 = 0.f, si1 = 0.f;
        const float2* tzp = (const float2*)(tzs + k * 84);
        const float4* X0 = (const float4*)(xr_ + xx * 40);
        const float4* X1 = (const float4*)(xr_ + (xx + 32) * 40);
        for (int zc = 0; zc < 10; zc++) {
            float4 A = X0[zc], B = X1[zc];
            float2 T0 = tzp[zc * 4], T1v = tzp[zc * 4 + 1];
            float2 T2v = tzp[zc * 4 + 2], T3v = tzp[zc * 4 + 3];
            sr0 = fmaf(A.x, T0.x, sr0);  si0 = fmaf(A.x, T0.y, si0);
            sr0 = fmaf(A.y, T1v.x, sr0); si0 = fmaf(A.y, T1v.y, si0);
            sr0 = fmaf(A.z, T2v.x, sr0); si0 = fmaf(A.z, T2v.y, si0);
            sr0 = fmaf(A.w, T3v.x, sr0); si0 = fmaf(A.w, T3v.y, si0);
            sr1 = fmaf(B.x, T0.x, sr1);  si1 = fmaf(B.x, T0.y, si1);
            sr1 = fmaf(B.y, T1v.x, sr1); si1 = fmaf(B.y, T1v.y, si1);
            sr1 = fmaf(B.z, T2v.x, sr1); si1 = fmaf(B.z, T2v.y, si1);
            sr1 = fmaf(B.w, T3v.x, sr1); si1 = fmaf(B.w, T3v.y, si1);
        }
        ((float2*)f1)[xx * 8 + k] = make_float2(sr0, si0);
        ((float2*)f1)[(xx + 32) * 8 + k] = make_float2(sr1, si1);
    }
    __syncthreads();
    if (t < 184) {
        int m = t >> 3, k = t & 7;
        float sr = 0.f, si = 0.f;
        const float2* f1p = (const float2*)f1;
        const float2* txp = (const float2*)txs;
        for (int xx = 0; xx < 64; xx++) {
            float2 a = f1p[xx * 8 + k];
            float2 w = txp[xx * 23 + m];
            sr = fmaf(a.x, w.x, sr); sr = fmaf(-a.y, w.y, sr);
            si = fmaf(a.x, w.y, si); si = fmaf(a.y, w.x, si);
        }
        size_t g = ((size_t)(((b * 64 + c) * 64 + y) * 23 + m) * 8 + k) * 2;
        Fx[g] = sr; Fx[g + 1] = si;
    }
}

// ---------------- forward y-DFT: thread=(n,kpair), b128 s + b64 table --------
__global__ __launch_bounds__(128) void k_fwd_y(const float* __restrict__ Fx,
        const float* __restrict__ txf, float* __restrict__ Xs) {
    int bid = blockIdx.x;
    int b = bid / 1472, rem = bid % 1472, c = rem / 23, m = rem % 23;
    int t = threadIdx.x;
    __shared__ __align__(16) float s[1024];    // [y][k][2]
    __shared__ __align__(16) float txs[2944];
    for (int idx = t; idx < 512; idx += 128) {
        int y = idx >> 3, k = idx & 7;
        size_t g = ((size_t)(((b * 64 + c) * 64 + y) * 23 + m) * 8 + k);
        ((float2*)s)[idx] = ((const float2*)Fx)[g];
    }
    for (int idx = t; idx < 736; idx += 128) ((float4*)txs)[idx] = ((const float4*)txf)[idx];
    __syncthreads();
    if (t < 92) {
        int n = t >> 2, kp = t & 3;
        float sr0 = 0.f, si0 = 0.f, sr1 = 0.f, si1 = 0.f;
        const float2* txp = (const float2*)txs;
        for (int y = 0; y < 64; y++) {
            float4 S = *(const float4*)&s[y * 16 + kp * 4];
            float2 w = txp[y * 23 + n];
            sr0 = fmaf(S.x, w.x, sr0); sr0 = fmaf(-S.y, w.y, sr0);
            si0 = fmaf(S.x, w.y, si0); si0 = fmaf(S.y, w.x, si0);
            sr1 = fmaf(S.z, w.x, sr1); sr1 = fmaf(-S.w, w.y, sr1);
            si1 = fmaf(S.z, w.y, si1); si1 = fmaf(S.w, w.x, si1);
        }
        size_t g = ((size_t)(((b * 64 + c) * 23 + n) * 23 + m)) * 16 + kp * 4;
        *(float4*)&Xs[g] = make_float4(sr0, si0, sr1, si1);
    }
}

// ---------------- mode mixing (unchanged) ----------------
__global__ void k_mix(const float* __restrict__ Xs, const float* __restrict__ WLC,
                      const float* __restrict__ WLR, float* __restrict__ Md) {
    int bid = blockIdx.x;
    int n = bid / 23, m = bid % 23;
    int a = n, c = m, yy, w;
    if (c >= 11) { yy = a; w = c - 11; } else { yy = 22 - a; w = 11 - c; }
    int isLC, idx;
    if (yy >= 12) {
        int p = yy - 12, q = w;
        if (q == 0) { isLC = 1; idx = p + 1; } else { isLC = 0; idx = p * 11 + (q - 1); }
    } else {
        if (w == 0) { isLC = 1; idx = 11 - yy; }
        else {
            int p = w - 1, q = 11 - yy;
            if (q == 0) { isLC = 1; idx = p + 1; } else { isLC = 0; idx = p * 11 + (q - 1); }
        }
    }
    const float* src = isLC ? WLC : WLR;
    int stride = isLC ? 96 : 968;
    int base8 = idx * 8;

    int t = threadIdx.x;
    int o = t >> 3, tt = t & 7;
    __shared__ __align__(16) float wl[8 * 64 * 8];
    __shared__ float xl[256];
    float aR0 = 0.f, aI0 = 0.f, aR1 = 0.f, aI1 = 0.f;
    for (int i0 = 0; i0 < 64; i0 += 8) {
        {
            int il = t >> 6, oo = t & 63;
            const float4* g = (const float4*)(src + (size_t)((i0 + il) * 64 + oo) * stride + base8);
            float4 A = g[0], B = g[1];
            float4* d = (float4*)&wl[(il * 64 + oo) * 8];
            d[0] = A; d[1] = B;
        }
        if (t < 256) {
            int bb = t >> 7, il = (t >> 4) & 7, kk = (t >> 1) & 7, ri = t & 1;
            xl[t] = Xs[((size_t)(((bb * 64 + i0 + il) * 23 + n) * 23 + m) * 8 + kk) * 2 + ri];
        }
        __syncthreads();
#pragma unroll
        for (int il = 0; il < 8; il++) {
            float wv = wl[(il * 64 + o) * 8 + tt];
            float xr0 = xl[(il * 8 + tt) * 2], xi0 = xl[(il * 8 + tt) * 2 + 1];
            float xr1 = xl[128 + (il * 8 + tt) * 2], xi1 = xl[128 + (il * 8 + tt) * 2 + 1];
            aR0 += wv * xr0; aI0 += wv * xi0;
            aR1 += wv * xr1; aI1 += wv * xi1;
        }
        __syncthreads();
    }
    size_t ob0 = ((size_t)((o * 23 + n) * 23 + m) * 8 + tt) * 2;
    size_t ob1 = ((size_t)(((64 + o) * 23 + n) * 23 + m) * 8 + tt) * 2;
    Md[ob0] = aR0; Md[ob0 + 1] = aI0;
    Md[ob1] = aR1; Md[ob1 + 1] = aI1;
}

// ---------------- inverse y: thread=(y,kpair) ----------------
__global__ __launch_bounds__(256) void k_inv_y(const float* __restrict__ Md,
        const float* __restrict__ txi, float* __restrict__ T1) {
    int bid = blockIdx.x;
    int b = bid / 1472, rem = bid % 1472, o = rem / 23, m = rem % 23;
    int t = threadIdx.x;
    __shared__ __align__(16) float s[368];     // [n][k][2]
    __shared__ __align__(16) float txs[2944];
    if (t < 184) {
        int n = t >> 3, kk = t & 7;
        size_t g = ((size_t)(((b * 64 + o) * 23 + n) * 23 + m) * 8 + kk);
        ((float2*)s)[t] = ((const float2*)Md)[g];
    }
    for (int idx = t; idx < 736; idx += 256) ((float4*)txs)[idx] = ((const float4*)txi)[idx];
    __syncthreads();
    int y = t >> 2, kp = t & 3;
    float sr0 = 0.f, si0 = 0.f, sr1 = 0.f, si1 = 0.f;
    const float2* txp = (const float2*)txs;
    for (int n = 0; n < 23; n++) {
        float4 S = *(const float4*)&s[n * 16 + kp * 4];
        float2 w = txp[y * 23 + n];
        sr0 = fmaf(S.x, w.x, sr0); sr0 = fmaf(-S.y, w.y, sr0);
        si0 = fmaf(S.x, w.y, si0); si0 = fmaf(S.y, w.x, si0);
        sr1 = fmaf(S.z, w.x, sr1); sr1 = fmaf(-S.w, w.y, sr1);
        si1 = fmaf(S.z, w.y, si1); si1 = fmaf(S.w, w.x, si1);
    }
    size_t g = ((size_t)(((b * 64 + o) * 64 + y) * 23 + m)) * 16 + kp * 4;
    *(float4*)&T1[g] = make_float4(sr0, si0, sr1, si1);
}

// ---------------- inverse x: thread=(xx,kpair) ----------------
__global__ __launch_bounds__(256) void k_inv_x(const float* __restrict__ T1,
        const float* __restrict__ txi, float* __restrict__ T2) {
    int bid = blockIdx.x;
    int b = bid >> 12, o = (bid >> 6) & 63, y = bid & 63;
    int t = threadIdx.x;
    __shared__ __align__(16) float s[368];     // [m][k][2]
    __shared__ __align__(16) float txs[2944];
    {
        const float4* src = (const float4*)(T1 + (size_t)((b * 64 + o) * 64 + y) * 368);
        if (t < 92) ((float4*)s)[t] = src[t];
    }
    for (int idx = t; idx < 736; idx += 256) ((float4*)txs)[idx] = ((const float4*)txi)[idx];
    __syncthreads();
    int xx = t >> 2, kp = t & 3;
    float sr0 = 0.f, si0 = 0.f, sr1 = 0.f, si1 = 0.f;
    const float2* txp = (const float2*)txs;
    for (int m = 0; m < 23; m++) {
        float4 S = *(const float4*)&s[m * 16 + kp * 4];
        float2 w = txp[xx * 23 + m];
        sr0 = fmaf(S.x, w.x, sr0); sr0 = fmaf(-S.y, w.y, sr0);
        si0 = fmaf(S.x, w.y, si0); si0 = fmaf(S.y, w.x, si0);
        sr1 = fmaf(S.z, w.x, sr1); sr1 = fmaf(-S.w, w.y, sr1);
        si1 = fmaf(S.z, w.y, si1); si1 = fmaf(S.w, w.x, si1);
    }
    size_t g = ((size_t)((b * 64 + o) * 4096 + y * 64 + xx)) * 16 + kp * 4;
    *(float4*)&T2[g] = make_float4(sr0, si0, sr1, si1);
}

// ---------------- inline erf-based GELU (A&S 7.1.26, |err|<=1.5e-7) ----
__device__ __forceinline__ float gelu_fast(float x) {
    float u = x * 0.70710678118654752f;
    float a = fabsf(u);
    float t = 1.0f / (1.0f + 0.3275911f * a);
    float poly = t * (0.254829592f + t * (-0.284496736f + t * (1.421413741f +
                 t * (-1.453152027f + t * 1.061405429f))));
    float erfa = 1.0f - poly * __expf(-a * a);
    float er = copysignf(erfa, u);
    return 0.5f * x * (1.0f + er);
}

// ---------------- mlp1: k-space GEMM + c2r + gelu (unchanged from R8) -------
__global__ __launch_bounds__(256) void k_mlp1(
    const float* __restrict__ t2buf, const float* __restrict__ w1t,
    const float* __restrict__ b1, const float* __restrict__ tz2g,
    float* __restrict__ g) {
    __shared__ __align__(16) float T2s[4096];   // [4 sites][64 i][16]
    __shared__ __align__(16) float w1ls[4096];  // [64 i][64 j]
    __shared__ __align__(16) float Hs[4096];    // [4 sites][64 j][16]
    __shared__ float tzls[640];
    int t = threadIdx.x;
    int site0 = blockIdx.x * 4;
    for (int idx = t; idx < 1024; idx += 256) {
        int sl = idx >> 8, r = idx & 255, i = r >> 2, q = r & 3;
        int site = site0 + sl;
        int b = site >> 12, yx = site & 4095;
        const float4* src = (const float4*)(t2buf + ((size_t)(b * 64 + i) * 4096 + yx) * 16 + q * 4);
        *(float4*)&T2s[sl * 1024 + i * 16 + q * 4] = *src;
    }
    for (int idx = t; idx < 1024; idx += 256)
        *(float4*)&w1ls[idx * 4] = ((const float4*)w1t)[idx];
    for (int idx = t; idx < 640; idx += 256) tzls[idx] = tz2g[idx];
    __syncthreads();
    {
        int sl = t >> 6, u = t & 63;
        int j0 = (u >> 2) * 4, kr0 = (u & 3) * 4;
        float c0 = 0.f, c1 = 0.f, c2 = 0.f, c3 = 0.f, c4 = 0.f, c5 = 0.f, c6 = 0.f, c7 = 0.f;
        float c8 = 0.f, c9 = 0.f, c10 = 0.f, c11 = 0.f, c12 = 0.f, c13 = 0.f, c14 = 0.f, c15 = 0.f;
        int tb = sl * 1024 + kr0;
        for (int i = 0; i < 64; i++) {
            float4 W = *(const float4*)&w1ls[i * 64 + j0];
            float4 T = *(const float4*)&T2s[tb + i * 16];
            c0  = fmaf(W.x, T.x, c0);  c1  = fmaf(W.x, T.y, c1);
            c2  = fmaf(W.x, T.z, c2);  c3  = fmaf(W.x, T.w, c3);
            c4  = fmaf(W.y, T.x, c4);  c5  = fmaf(W.y, T.y, c5);
            c6  = fmaf(W.y, T.z, c6);  c7  = fmaf(W.y, T.w, c7);
            c8  = fmaf(W.z, T.x, c8);  c9  = fmaf(W.z, T.y, c9);
            c10 = fmaf(W.z, T.z, c10); c11 = fmaf(W.z, T.w, c11);
            c12 = fmaf(W.w, T.x, c12); c13 = fmaf(W.w, T.y, c13);
            c14 = fmaf(W.w, T.z, c14); c15 = fmaf(W.w, T.w, c15);
        }
        int hb = sl * 1024 + j0 * 16 + kr0;
        *(float4*)&Hs[hb]      = make_float4(c0, c1, c2, c3);
        *(float4*)&Hs[hb + 16] = make_float4(c4, c5, c6, c7);
        *(float4*)&Hs[hb + 32] = make_float4(c8, c9, c10, c11);
        *(float4*)&Hs[hb + 48] = make_float4(c12, c13, c14, c15);
    }
    __syncthreads();
    {
        int sl = t >> 6, j = t & 63;
        int site = site0 + sl;
        int b = site >> 12, yx = site & 4095;
        int hb = sl * 1024 + j * 16;
        float4 H0 = *(const float4*)&Hs[hb];
        float4 H1 = *(const float4*)&Hs[hb + 4];
        float4 H2 = *(const float4*)&Hs[hb + 8];
        float4 H3 = *(const float4*)&Hs[hb + 12];
        float b1j = b1[j];
        size_t obase = (size_t)j * 327680 + (size_t)b * 163840 + yx * 40;
        for (int zc = 0; zc < 10; zc++) {
            float4 outv;
#pragma unroll
            for (int zi = 0; zi < 4; zi++) {
                int z = zc * 4 + zi;
                const float4* tz = (const float4*)&tzls[z * 16];
                float4 T0 = tz[0], T1v = tz[1], T2v = tz[2], T3 = tz[3];
                float v = H0.x * T0.x;
                v = fmaf(H0.y, T0.y, v); v = fmaf(H0.z, T0.z, v); v = fmaf(H0.w, T0.w, v);
                v = fmaf(H1.x, T1v.x, v); v = fmaf(H1.y, T1v.y, v);
                v = fmaf(H1.z, T1v.z, v); v = fmaf(H1.w, T1v.w, v);
                v = fmaf(H2.x, T2v.x, v); v = fmaf(H2.y, T2v.y, v);
                v = fmaf(H2.z, T2v.z, v); v = fmaf(H2.w, T2v.w, v);
                v = fmaf(H3.x, T3.x, v); v = fmaf(H3.y, T3.y, v);
                v = fmaf(H3.z, T3.z, v); v = fmaf(H3.w, T3.w, v);
                float h = b1j + v;
                float gv = gelu_fast(h);
                if (zi == 0) outv.x = gv; else if (zi == 1) outv.y = gv;
                else if (zi == 2) outv.z = gv; else outv.w = gv;
            }
            *(float4*)&g[obase + zc * 4] = outv;
        }
    }
}

// ---------------- mlp2 v3: 8o x 8p register tile, x/g from GLOBAL -----------
// LDS delivers only weights (2 b128 per 64 FMA-inst). 256 points/block, in-place
// safe: block touches only its own point range; x reads precede stores.
#define FMAR8(R, Wc) \
    a##R##0 = fmaf(Wc, X0.x, a##R##0); a##R##1 = fmaf(Wc, X0.y, a##R##1); \
    a##R##2 = fmaf(Wc, X0.z, a##R##2); a##R##3 = fmaf(Wc, X0.w, a##R##3); \
    a##R##4 = fmaf(Wc, X1.x, a##R##4); a##R##5 = fmaf(Wc, X1.y, a##R##5); \
    a##R##6 = fmaf(Wc, X1.z, a##R##6); a##R##7 = fmaf(Wc, X1.w, a##R##7);

__global__ __launch_bounds__(256) void k_mlp2(
    const float* __restrict__ g, float* __restrict__ x,
    const float* __restrict__ w2t, const float* __restrict__ b2,
    const float* __restrict__ wwt, const float* __restrict__ wb, int dorelu) {
    __shared__ __align__(16) float wls[4096];  // [64][64]
    int t = threadIdx.x;
    int P0 = blockIdx.x * 256;
    int b = P0 / 163840, pl = P0 % 163840;
    size_t xbase = (size_t)b * 10485760 + pl;
    int o0 = (t >> 5) * 8, p0 = (t & 31) * 8;
#define INITR(R) float a##R##0 = b2[o0 + R] + wb[o0 + R]; \
    float a##R##1 = a##R##0, a##R##2 = a##R##0, a##R##3 = a##R##0, \
          a##R##4 = a##R##0, a##R##5 = a##R##0, a##R##6 = a##R##0, a##R##7 = a##R##0;
    INITR(0) INITR(1) INITR(2) INITR(3) INITR(4) INITR(5) INITR(6) INITR(7)
#undef INITR
    for (int idx = t; idx < 1024; idx += 256)
        ((float4*)wls)[idx] = ((const float4*)wwt)[idx];
    __syncthreads();
    for (int i = 0; i < 64; i++) {
        const float4* wp = (const float4*)&wls[i * 64 + o0];
        float4 W0 = wp[0], W1 = wp[1];
        const float* xp = x + xbase + (size_t)i * 163840 + p0;
        float4 X0 = *(const float4*)xp, X1 = *(const float4*)(xp + 4);
        FMAR8(0, W0.x) FMAR8(1, W0.y) FMAR8(2, W0.z) FMAR8(3, W0.w)
        FMAR8(4, W1.x) FMAR8(5, W1.y) FMAR8(6, W1.z) FMAR8(7, W1.w)
    }
    __syncthreads();
    for (int idx = t; idx < 1024; idx += 256)
        ((float4*)wls)[idx] = ((const float4*)w2t)[idx];
    __syncthreads();
    for (int j = 0; j < 64; j++) {
        const float4* wp = (const float4*)&wls[j * 64 + o0];
        float4 W0 = wp[0], W1 = wp[1];
        const float* gp = g + (size_t)j * 327680 + P0 + p0;
        float4 X0 = *(const float4*)gp, X1 = *(const float4*)(gp + 4);
        FMAR8(0, W0.x) FMAR8(1, W0.y) FMAR8(2, W0.z) FMAR8(3, W0.w)
        FMAR8(4, W1.x) FMAR8(5, W1.y) FMAR8(6, W1.z) FMAR8(7, W1.w)
    }
#define STROW(R) { \
        float4 R0, R1; \
        if (dorelu) { \
            R0 = make_float4(fmaxf(a##R##0, 0.f), fmaxf(a##R##1, 0.f), fmaxf(a##R##2, 0.f), fmaxf(a##R##3, 0.f)); \
            R1 = make_float4(fmaxf(a##R##4, 0.f), fmaxf(a##R##5, 0.f), fmaxf(a##R##6, 0.f), fmaxf(a##R##7, 0.f)); \
        } else { \
            R0 = make_float4(a##R##0, a##R##1, a##R##2, a##R##3); \
            R1 = make_float4(a##R##4, a##R##5, a##R##6, a##R##7); \
        } \
        float* op = x + xbase + (size_t)(o0 + R) * 163840 + p0; \
        *(float4*)op = R0; *(float4*)(op + 4) = R1; }
    STROW(0) STROW(1) STROW(2) STROW(3) STROW(4) STROW(5) STROW(6) STROW(7)
#undef STROW
}

// ---------------- final head (unchanged from R8) ----------------
#define FR24(V, PA, PB, n0, n1, n2, n3) \
    PA = fmaf(V.x, xa##n0, PA); PB = fmaf(V.x, xb##n0, PB); \
    PA = fmaf(V.y, xa##n1, PA); PB = fmaf(V.y, xb##n1, PB); \
    PA = fmaf(V.z, xa##n2, PA); PB = fmaf(V.z, xb##n2, PB); \
    PA = fmaf(V.w, xa##n3, PA); PB = fmaf(V.w, xb##n3, PB);

#define FMAROW2_ALL(wb) { const float4* _w = (wb); float4 V; \
    V=_w[0];  FR24(V,pa0,pb0,0,1,2,3)     V=_w[1];  FR24(V,pa1,pb1,4,5,6,7) \
    V=_w[2];  FR24(V,pa2,pb2,8,9,10,11)   V=_w[3];  FR24(V,pa3,pb3,12,13,14,15) \
    V=_w[4];  FR24(V,pa0,pb0,16,17,18,19) V=_w[5];  FR24(V,pa1,pb1,20,21,22,23) \
    V=_w[6];  FR24(V,pa2,pb2,24,25,26,27) V=_w[7];  FR24(V,pa3,pb3,28,29,30,31) \
    V=_w[8];  FR24(V,pa0,pb0,32,33,34,35) V=_w[9];  FR24(V,pa1,pb1,36,37,38,39) \
    V=_w[10]; FR24(V,pa2,pb2,40,41,42,43) V=_w[11]; FR24(V,pa3,pb3,44,45,46,47) \
    V=_w[12]; FR24(V,pa0,pb0,48,49,50,51) V=_w[13]; FR24(V,pa1,pb1,52,53,54,55) \
    V=_w[14]; FR24(V,pa2,pb2,56,57,58,59) V=_w[15]; FR24(V,pa3,pb3,60,61,62,63) }

__global__ __launch_bounds__(256, 3) void k_head(
    const float* __restrict__ xcur,
    const float* __restrict__ qw1, const float* __restrict__ qb1,
    const float* __restrict__ qw2, const float* __restrict__ qb2,
    float* __restrict__ outp) {
    __shared__ float4 wls[1024];
    int t = threadIdx.x;
    int P0 = blockIdx.x * 512;
    int b = P0 / 163840, pl = P0 % 163840;
    size_t baseA = (size_t)b * 10485760 + pl + t;
    size_t baseB = baseA + 256;
#define LDA(n) float xa##n = xcur[baseA + (size_t)(n) * 163840];
    REP64(LDA)
#undef LDA
#define LDB(n) float xb##n = xcur[baseB + (size_t)(n) * 163840];
    REP64(LDB)
#undef LDB
    float accA = qb2[0], accB = qb2[0];
    for (int c = 0; c < 4; c++) {
        __syncthreads();
        const float4* src = (const float4*)(qw1 + c * 4096);
        for (int idx = t; idx < 1024; idx += 256) wls[idx] = src[idx];
        __syncthreads();
        for (int jl = 0; jl < 64; jl++) {
            int j = c * 64 + jl;
            float pa0 = 0.f, pa1 = 0.f, pa2 = 0.f, pa3 = 0.f;
            float pb0 = 0.f, pb1 = 0.f, pb2 = 0.f, pb3 = 0.f;
            FMAROW2_ALL(&wls[jl * 16])
            float bj = qb1[j], wj = qw2[j];
            float hA = bj + ((pa0 + pa1) + (pa2 + pa3));
            float hB = bj + ((pb0 + pb1) + (pb2 + pb3));
            accA += wj * gelu_fast(hA);
            accB += wj * gelu_fast(hB);
        }
    }
    outp[P0 + t] = accA;
    outp[P0 + 256 + t] = accB;
}

extern "C" void kernel_launch(void* const* d_in, const int* in_sizes, int n_in,
                              void* d_out, int out_size, void* d_ws, size_t ws_size,
                              hipStream_t stream) {
    const float* x_in = (const float*)d_in[0];
    const float* p_w  = (const float*)d_in[1];
    const float* p_b  = (const float*)d_in[2];
    const float* W_LC = (const float*)d_in[3];
    const float* W_LR = (const float*)d_in[4];
    const float* m_w1 = (const float*)d_in[5];
    const float* m_b1 = (const float*)d_in[6];
    const float* m_w2 = (const float*)d_in[7];
    const float* m_b2 = (const float*)d_in[8];
    const float* w_w  = (const float*)d_in[9];
    const float* w_b  = (const float*)d_in[10];
    const float* q_w1 = (const float*)d_in[11];
    const float* q_b1 = (const float*)d_in[12];
    const float* q_w2 = (const float*)d_in[13];
    const float* q_b2 = (const float*)d_in[14];

    char* ws = (char*)d_ws;
    // table region [0, 65536)
    float* tzf = (float*)(ws + 0);        // 2560 B
    float* tzi = (float*)(ws + 2560);     // 2560 B
    float* tz2 = (float*)(ws + 5120);     // 2560 B
    float* tzk = (float*)(ws + 7680);     // 2560 B
    float* txf = (float*)(ws + 10240);    // 11776 B
    float* txi = (float*)(ws + 22016);    // 11776 B -> 33792
    float* w2t = (float*)(ws + 65536);
    float* wwt = (float*)(ws + 131072);
    float* w1t = (float*)(ws + 196608);
    size_t off = 262144;
    float* xA = (float*)(ws + off); off += 83886080ull;
    float* gbuf = (float*)(ws + off); off += 83886080ull;
    float* Fx = (float*)(ws + off); off += 12058624ull;
    float* Xs = (float*)(ws + off); off += 4333568ull;
    float* Md = (float*)(ws + off); off += 4333568ull;
    float* T1 = (float*)(ws + off); off += 12058624ull;
    float* T2 = (float*)(ws + off); off += 33554432ull;

    k_tables<<<6, 256, 0, stream>>>(tzf, tzi, tz2, tzk, txf, txi);
    k_wtrans<<<64, 256, 0, stream>>>(m_w2, w_w, m_w1, w2t, wwt, w1t);
    k_lift<<<1280, 256, 0, stream>>>(x_in, p_w, p_b, xA);

    for (int l = 0; l < 4; l++) {
        k_fwd_zx<<<8192, 256, 0, stream>>>(xA, tzk, txf, Fx);
        k_fwd_y<<<2944, 128, 0, stream>>>(Fx, txf, Xs);
        k_mix<<<529, 512, 0, stream>>>(Xs, W_LC + (size_t)l * 393216,
                                       W_LR + (size_t)l * 3964928, Md);
        k_inv_y<<<2944, 256, 0, stream>>>(Md, txi, T1);
        k_inv_x<<<8192, 256, 0, stream>>>(T1, txi, T2);
        k_mlp1<<<2048, 256, 0, stream>>>(T2, w1t + (size_t)l * 4096, m_b1 + l * 64,
                                         tz2, gbuf);
        k_mlp2<<<1280, 256, 0, stream>>>(gbuf, xA, w2t + (size_t)l * 4096, m_b2 + l * 64,
                                         wwt + (size_t)l * 4096, w_b + l * 64,
                                         (l < 3) ? 1 : 0);
    }
    k_head<<<640, 256, 0, stream>>>(xA, q_w1, q_b1, q_w2, q_b2, (float*)d_out);
}